// Round 1
// baseline (1741.635 us; speedup 1.0000x reference)
//
#include <hip/hip_runtime.h>

// Fused tanh-RNN forward: x[B,784] -> softmax(FC(h_T)) for B=65536, T=28, I=28, H=64, C=10.
// Mapping A: one sample per thread, h[64] fully in VGPRs, weights streamed as
// wave-uniform scalar loads (s_load + v_fmac v,s,v). Compute-bound on fp32 VALU.

namespace {

constexpr int T = 28;
constexpr int I = 28;
constexpr int H = 64;
constexpr int C = 10;

__device__ __forceinline__ float fast_tanh(float xx) {
    // tanh(x) = 1 - 2/(exp(2x)+1); exp via v_exp_f32, rcp via v_rcp_f32 (~1 ulp).
    // Saturates correctly: exp->inf => 1.0, exp->0 => -1.0. No NaNs for finite x.
    float e = __expf(2.0f * xx);
    float r = __builtin_amdgcn_rcpf(e + 1.0f);
    return fmaf(-2.0f, r, 1.0f);
}

__global__ __launch_bounds__(256, 1) void rnn_fused(
    const float* __restrict__ x,
    const float* __restrict__ W_ih,   // [H][I]
    const float* __restrict__ W_hh,   // [H][H]
    const float* __restrict__ b_ih,   // [H]
    const float* __restrict__ b_hh,   // [H]
    const float* __restrict__ fc_w,   // [C][H]
    const float* __restrict__ fc_b,   // [C]
    float* __restrict__ out,          // [B][C]
    int nB)
{
    const int s = blockIdx.x * blockDim.x + threadIdx.x;
    if (s >= nB) return;
    const float* __restrict__ xrow = x + (size_t)s * (T * I);

    float h[H];
    float xt[I];

    // ---- t = 0: h = tanh(x_0 @ W_ih^T + b)  (h0 == 0, recurrent term skipped) ----
    #pragma unroll
    for (int q = 0; q < I / 4; ++q) {
        const float4 v = *reinterpret_cast<const float4*>(xrow + q * 4);
        xt[q * 4 + 0] = v.x; xt[q * 4 + 1] = v.y;
        xt[q * 4 + 2] = v.z; xt[q * 4 + 3] = v.w;
    }
    #pragma unroll
    for (int j = 0; j < H; ++j) {
        float acc = b_ih[j] + b_hh[j];      // wave-uniform -> scalar pipe
        #pragma unroll
        for (int i = 0; i < I; ++i)
            acc = fmaf(xt[i], W_ih[j * I + i], acc);
        h[j] = fast_tanh(acc);
    }

    // ---- t = 1 .. T-1: h = tanh(x_t @ W_ih^T + b + h @ W_hh^T) ----
    for (int t = 1; t < T; ++t) {
        #pragma unroll
        for (int q = 0; q < I / 4; ++q) {
            const float4 v = *reinterpret_cast<const float4*>(xrow + t * I + q * 4);
            xt[q * 4 + 0] = v.x; xt[q * 4 + 1] = v.y;
            xt[q * 4 + 2] = v.z; xt[q * 4 + 3] = v.w;
        }
        float hn[H];
        #pragma unroll
        for (int j = 0; j < H; ++j) {
            float acc = b_ih[j] + b_hh[j];
            #pragma unroll
            for (int i = 0; i < I; ++i)
                acc = fmaf(xt[i], W_ih[j * I + i], acc);
            #pragma unroll
            for (int k = 0; k < H; ++k)
                acc = fmaf(h[k], W_hh[j * H + k], acc);
            hn[j] = fast_tanh(acc);
        }
        #pragma unroll
        for (int j = 0; j < H; ++j) h[j] = hn[j];
    }

    // ---- FC + softmax ----
    float logits[C];
    #pragma unroll
    for (int c = 0; c < C; ++c) {
        float acc = fc_b[c];
        #pragma unroll
        for (int k = 0; k < H; ++k)
            acc = fmaf(h[k], fc_w[c * H + k], acc);
        logits[c] = acc;
    }
    float m = logits[0];
    #pragma unroll
    for (int c = 1; c < C; ++c) m = fmaxf(m, logits[c]);
    float sum = 0.0f;
    #pragma unroll
    for (int c = 0; c < C; ++c) {
        const float e = __expf(logits[c] - m);
        logits[c] = e;
        sum += e;
    }
    float r = __builtin_amdgcn_rcpf(sum);
    r = r * (2.0f - sum * r);               // one Newton step -> ~0.5 ulp
    #pragma unroll
    for (int c = 0; c < C; ++c)
        out[s * C + c] = logits[c] * r;
}

} // namespace

extern "C" void kernel_launch(void* const* d_in, const int* in_sizes, int n_in,
                              void* d_out, int out_size, void* d_ws, size_t ws_size,
                              hipStream_t stream) {
    const float* x    = (const float*)d_in[0];
    const float* W_ih = (const float*)d_in[1];
    const float* W_hh = (const float*)d_in[2];
    const float* b_ih = (const float*)d_in[3];
    const float* b_hh = (const float*)d_in[4];
    const float* fc_w = (const float*)d_in[5];
    const float* fc_b = (const float*)d_in[6];
    float* out = (float*)d_out;

    const int nB = in_sizes[0] / (T * I);   // 65536
    const int block = 256;
    const int grid = (nB + block - 1) / block;
    rnn_fused<<<grid, block, 0, stream>>>(x, W_ih, W_hh, b_ih, b_hh, fc_w, fc_b, out, nB);
}